// Round 8
// baseline (6553.027 us; speedup 1.0000x reference)
//
#include <hip/hip_runtime.h>
#include <hip/hip_bf16.h>

// ScalarBorn: 4th-order FD scalar wave + Born scattering with CPML, MI355X.
// R8: one kernel/step, 888 blocks (row x shot-pair), 2 shots per block for
// ILP, ONE barrier (psi_x_new neighbors recomputed in registers from LDS
// w + psi_x_old rows). R7 showed load count isn't the limiter; this round
// targets block latency (rounds/CU halved, loads batched before barrier).

constexpr int NYX  = 400;
constexpr int NS   = 4;
constexpr int NREC = 100;
constexpr int NT   = 300;
constexpr int PAD  = 22;
constexpr int NP   = 444;
constexpr int NP2  = NP * NP;          // 197136
constexpr int SNP2 = NS * NP2;         // 788544
constexpr float DT    = 0.0005f;
constexpr float INVH  = 0.2f;          // 1/DX
constexpr float INVH2 = 0.04f;         // 1/DX^2
constexpr float C1A = 1.0f / 12.0f;
constexpr float C1B = 2.0f / 3.0f;
constexpr float C2A = -1.0f / 12.0f;
constexpr float C2B = 4.0f / 3.0f;
constexpr float C2C = -2.5f;

__device__ __align__(16) float g_wb[2][SNP2];      // bg field ping-pong
__device__ __align__(16) float g_ws[2][SNP2];      // scattered field ping-pong
__device__ __align__(16) float g_psi[2][4][SNP2];  // [buf][py_b,px_b,py_s,px_s]
__device__ __align__(16) float g_zeta[4][SNP2];    // [zy_b,zx_b,zy_s,zx_s]
__device__ float g_v2dt2[NP2];
__device__ float g_bscale[NP2];
__device__ float g_pa[NP];
__device__ float g_pb[NP];
__device__ float g_fbg[NT * NS];
__device__ float g_fsc[NT * NS];
__device__ int   g_spos[2 * NS];
__device__ int   g_mode;               // 1 = bf16 io, 0 = f32 io

__device__ __forceinline__ int clampi(int v, int lo, int hi) {
    return v < lo ? lo : (v > hi ? hi : v);
}
__device__ __forceinline__ float in_ld(const void* p, int i) {
    if (g_mode) return __bfloat162float(((const __hip_bfloat16*)p)[i]);
    return ((const float*)p)[i];
}
__device__ __forceinline__ void out_st(void* p, int i, float v) {
    if (g_mode) ((__hip_bfloat16*)p)[i] = __float2bfloat16(v);
    else        ((float*)p)[i] = v;
}
__device__ __forceinline__ float ld(const float* w, int y, int x) {
    if ((unsigned)y >= (unsigned)NP || (unsigned)x >= (unsigned)NP) return 0.f;
    return w[y * NP + x];
}

__global__ void detect_mode(const void* vptr) {
    if (threadIdx.x == 0 && blockIdx.x == 0) {
        const __hip_bfloat16* p = (const __hip_bfloat16*)vptr;
        int ok = 1;
        for (int i = 0; i < 32; i += 2) {
            float f = __bfloat162float(p[i]);
            if (!(f >= 1000.f && f <= 3000.f)) ok = 0;
        }
        g_mode = ok;
    }
}

__global__ void zero_state() {
    int i = blockIdx.x * blockDim.x + threadIdx.x;
    if (i >= NP2) return;                 // SNP2/4 float4s per array == NP2
    float4 z = make_float4(0.f, 0.f, 0.f, 0.f);
    ((float4*)g_wb[0])[i] = z;  ((float4*)g_wb[1])[i] = z;
    ((float4*)g_ws[0])[i] = z;  ((float4*)g_ws[1])[i] = z;
    #pragma unroll
    for (int b = 0; b < 2; ++b)
        #pragma unroll
        for (int k = 0; k < 4; ++k) ((float4*)g_psi[b][k])[i] = z;
    #pragma unroll
    for (int k = 0; k < 4; ++k) ((float4*)g_zeta[k])[i] = z;
}

__global__ void prep_pad(const void* __restrict__ v, const void* __restrict__ sc) {
    int i = blockIdx.x * blockDim.x + threadIdx.x;
    if (i >= NP2) return;
    int y = i / NP, x = i % NP;
    int vy = clampi(y - PAD, 0, NYX - 1);
    int vx = clampi(x - PAD, 0, NYX - 1);
    float vv = in_ld(v, vy * NYX + vx);
    float vd = vv * DT;
    g_v2dt2[i] = vd * vd;
    float s = 0.f;
    if (y >= PAD && y < PAD + NYX && x >= PAD && x < PAD + NYX)
        s = in_ld(sc, (y - PAD) * NYX + (x - PAD));
    g_bscale[i] = 2.f * vv * s * DT * DT;
    if (i < NP) {
        float fi = (float)i;
        float f1 = fminf(fmaxf((22.f - fi) * 0.05f, 0.f), 1.f);
        float f2 = fminf(fmaxf((fi - 421.f) * 0.05f, 0.f), 1.f);
        float frac = fmaxf(f1, f2);
        float sigma = 259.0408229f * frac * frac;
        const float alpha = 78.53981634f;
        float a = expf(-(sigma + alpha) * DT);
        g_pa[i] = a;
        g_pb[i] = (sigma > 0.f) ? sigma / (sigma + alpha) * (a - 1.f) : 0.f;
    }
}

__global__ void prep_src(const void* __restrict__ amp, const int* __restrict__ sloc,
                         const void* __restrict__ v, const void* __restrict__ sc) {
    int i = blockIdx.x * blockDim.x + threadIdx.x;
    if (i >= NT * NS) return;
    int s = i % NS, t = i / NS;
    int ly = clampi(sloc[s * 2 + 0], 0, NYX - 1);
    int lx = clampi(sloc[s * 2 + 1], 0, NYX - 1);
    float a  = in_ld(amp, s * NT + t);
    float vv = in_ld(v,  ly * NYX + lx);
    float ss = in_ld(sc, ly * NYX + lx);
    g_fbg[i] = -a * vv * vv * DT * DT;
    g_fsc[i] = -2.f * a * vv * ss * DT * DT;
    if (i < NS) {
        g_spos[2 * i]     = ly + PAD;
        g_spos[2 * i + 1] = lx + PAD;
    }
}

// one fused timestep. Block = row y, shots {2*bz, 2*bz+1}. 448 threads.
__global__ void __launch_bounds__(448)
step_fused(int t, const int* __restrict__ rloc, const int* __restrict__ rbloc,
           void* __restrict__ out) {
    const int x  = threadIdx.x;
    const int y  = blockIdx.y;
    const int sp = blockIdx.z;               // shot pair
    const int cur = t & 1, nxt = cur ^ 1;
    // w rows at offset 4 (zeros [0,4) & [448,452]); psi_x_old rows at offset 2
    __shared__ float swb[2][456], sws[2][456];
    __shared__ float spb[2][452], sps[2][452];

    // record step t-1 from buffer cur (read-only this dispatch)
    if (t > 0 && y == 0 && sp == 0) {
        for (int k = x; k < 2 * NS * NREC; k += 448) {
            bool isbg = k < NS * NREC;
            int  j = isbg ? k : k - NS * NREC;
            int  s = j / NREC, r = j % NREC;
            const int* rl = isbg ? rbloc : rloc;
            int ry = clampi(rl[(s * NREC + r) * 2 + 0], 0, NYX - 1) + PAD;
            int rx = clampi(rl[(s * NREC + r) * 2 + 1], 0, NYX - 1) + PAD;
            const float* w = isbg ? g_wb[cur] : g_ws[cur];
            float val = w[s * NP2 + ry * NP + rx];
            int base = isbg ? (2 * SNP2) : (2 * SNP2 + NS * NREC * NT);
            out_st(out, base + (s * NREC + r) * NT + (t - 1), val);
        }
    }

    const bool active = x < NP;
    const bool yframe = (y <= 23 || y >= 420);
    const int yx  = y * NP + x;
    const int lx4 = x + 4, lx2 = x + 2;
    const float pbx = (active ? g_pb[x] : 0.f);
    const float pax = (active ? g_pa[x] : 0.f);
    const float pby = g_pb[y];

    // ---- phase 1: batch-issue loads for both shots, stage LDS ----
    float wbv[2], wsv[2], prevb[2], prevs[2];
    float ynb[2][4], yns[2][4];              // interior y-neighbors
    float zxo_b[2], zxo_s[2], zyo_b[2], zyo_s[2];
    float v2 = 0.f, bsc = 0.f;
    if (active) { v2 = g_v2dt2[yx]; bsc = g_bscale[yx]; }
    #pragma unroll
    for (int j = 0; j < 2; ++j) {
        const int s = 2 * sp + j;
        const int idx = s * NP2 + yx;
        const float* wb  = g_wb[cur] + s * NP2;
        const float* wsc = g_ws[cur] + s * NP2;
        float b = 0.f, sv = 0.f, pxb = 0.f, pxs = 0.f;
        if (active) {
            b  = wb[yx];
            sv = wsc[yx];
            prevb[j] = g_wb[nxt][idx];
            prevs[j] = g_ws[nxt][idx];
            if (x <= 25 || x >= 418) {       // psi_x_old needed region
                pxb = g_psi[cur][1][idx];
                pxs = g_psi[cur][3][idx];
            }
            if (!yframe) {                   // rows y+-1, y+-2 always in range
                ynb[j][0] = wb[yx - 2 * NP];  ynb[j][1] = wb[yx - NP];
                ynb[j][2] = wb[yx + NP];      ynb[j][3] = wb[yx + 2 * NP];
                yns[j][0] = wsc[yx - 2 * NP]; yns[j][1] = wsc[yx - NP];
                yns[j][2] = wsc[yx + NP];     yns[j][3] = wsc[yx + 2 * NP];
            }
            if (pbx != 0.f) { zxo_b[j] = g_zeta[1][idx]; zxo_s[j] = g_zeta[3][idx]; }
            if (pby != 0.f) { zyo_b[j] = g_zeta[0][idx]; zyo_s[j] = g_zeta[2][idx]; }
        }
        wbv[j] = b;  wsv[j] = sv;
        swb[j][lx4] = b;   sws[j][lx4] = sv;    // inactive threads write 0 at 448..451
        spb[j][lx2] = pxb; sps[j][lx2] = pxs;   // inactive threads write 0 at 446..449
        if (x < 4) { swb[j][x] = 0.f; sws[j][x] = 0.f; }
        if (x < 2) { spb[j][x] = 0.f; sps[j][x] = 0.f; }
    }
    __syncthreads();
    if (!active) return;

    const bool xderiv = (x <= 23 || x >= 420);
    #pragma unroll
    for (int j = 0; j < 2; ++j) {
        const int s = 2 * sp + j;
        const int idx = s * NP2 + yx;
        const float* wb  = g_wb[cur] + s * NP2;
        const float* wsc = g_ws[cur] + s * NP2;

        // ---- x stencils from LDS ----
        float bm2 = swb[j][lx4 - 2], bm1 = swb[j][lx4 - 1];
        float bp1 = swb[j][lx4 + 1], bp2 = swb[j][lx4 + 2];
        float sm2 = sws[j][lx4 - 2], sm1 = sws[j][lx4 - 1];
        float sp1 = sws[j][lx4 + 1], sp2 = sws[j][lx4 + 2];
        float d2x_b = (C2A * (bm2 + bp2) + C2B * (bm1 + bp1) + C2C * wbv[j]) * INVH2;
        float d2x_s = (C2A * (sm2 + sp2) + C2B * (sm1 + sp1) + C2C * wsv[j]) * INVH2;

        // own psi_x update -> next buffer
        if (pbx != 0.f) {
            float dwx_b = (C1A * bm2 - C1B * bm1 + C1B * bp1 - C1A * bp2) * INVH;
            float dwx_s = (C1A * sm2 - C1B * sm1 + C1B * sp1 - C1A * sp2) * INVH;
            g_psi[nxt][1][idx] = pax * spb[j][lx2] + pbx * dwx_b;
            g_psi[nxt][3][idx] = pax * sps[j][lx2] + pbx * dwx_s;
        }

        // dpsi_x: recompute neighbors' psi_x_new from LDS (no 2nd barrier)
        float dpx_b = 0.f, dpx_s = 0.f;
        if (xderiv) {
            float pnb[5], pns[5];
            #pragma unroll
            for (int k = 0; k < 5; ++k) {
                int xx = x - 2 + k;
                float pbv = ((unsigned)xx < (unsigned)NP) ? g_pb[xx] : 0.f;
                float b_ = 0.f, s_ = 0.f;
                if (pbv != 0.f) {
                    float pav = g_pa[xx];
                    int li = xx + 4;
                    float db = (C1A * swb[j][li - 2] - C1B * swb[j][li - 1]
                              + C1B * swb[j][li + 1] - C1A * swb[j][li + 2]) * INVH;
                    float ds = (C1A * sws[j][li - 2] - C1B * sws[j][li - 1]
                              + C1B * sws[j][li + 1] - C1A * sws[j][li + 2]) * INVH;
                    b_ = pav * spb[j][xx + 2] + pbv * db;
                    s_ = pav * sps[j][xx + 2] + pbv * ds;
                }
                pnb[k] = b_; pns[k] = s_;
            }
            dpx_b = (C1A * pnb[0] - C1B * pnb[1] + C1B * pnb[3] - C1A * pnb[4]) * INVH;
            dpx_s = (C1A * pns[0] - C1B * pns[1] + C1B * pns[3] - C1A * pns[4]) * INVH;
        }

        // ---- y direction ----
        float d2y_b, d2y_s, dpy_b = 0.f, dpy_s = 0.f;
        if (yframe) {
            float wyb[9], wys[9];            // rows y-4..y+4, column x
            #pragma unroll
            for (int k = 0; k < 9; ++k) {
                if (k == 4) { wyb[4] = wbv[j]; wys[4] = wsv[j]; }
                else        { wyb[k] = ld(wb, y - 4 + k, x); wys[k] = ld(wsc, y - 4 + k, x); }
            }
            d2y_b = (C2A * (wyb[2] + wyb[6]) + C2B * (wyb[3] + wyb[5]) + C2C * wyb[4]) * INVH2;
            d2y_s = (C2A * (wys[2] + wys[6]) + C2B * (wys[3] + wys[5]) + C2C * wys[4]) * INVH2;
            float pnb[5], pns[5];
            #pragma unroll
            for (int k = 0; k < 5; ++k) {
                int yy = y - 2 + k;
                float pbv = ((unsigned)yy < (unsigned)NP) ? g_pb[yy] : 0.f;
                float b_ = 0.f, s_ = 0.f;
                if (pbv != 0.f) {
                    float pav = g_pa[yy];
                    float db = (C1A * wyb[k] - C1B * wyb[k + 1]
                              + C1B * wyb[k + 3] - C1A * wyb[k + 4]) * INVH;
                    float ds = (C1A * wys[k] - C1B * wys[k + 1]
                              + C1B * wys[k + 3] - C1A * wys[k + 4]) * INVH;
                    b_ = pav * g_psi[cur][0][s * NP2 + yy * NP + x] + pbv * db;
                    s_ = pav * g_psi[cur][2][s * NP2 + yy * NP + x] + pbv * ds;
                }
                pnb[k] = b_; pns[k] = s_;
            }
            dpy_b = (C1A * pnb[0] - C1B * pnb[1] + C1B * pnb[3] - C1A * pnb[4]) * INVH;
            dpy_s = (C1A * pns[0] - C1B * pns[1] + C1B * pns[3] - C1A * pns[4]) * INVH;
            if (pby != 0.f) {
                g_psi[nxt][0][idx] = pnb[2];
                g_psi[nxt][2][idx] = pns[2];
            }
        } else {
            d2y_b = (C2A * (ynb[j][0] + ynb[j][3]) + C2B * (ynb[j][1] + ynb[j][2])
                   + C2C * wbv[j]) * INVH2;
            d2y_s = (C2A * (yns[j][0] + yns[j][3]) + C2B * (yns[j][1] + yns[j][2])
                   + C2C * wsv[j]) * INVH2;
        }

        // ---- zeta (in-place, own point) ----
        float zy_b = 0.f, zy_s = 0.f, zx_b = 0.f, zx_s = 0.f;
        if (pby != 0.f) {
            float pay = g_pa[y];
            zy_b = pay * zyo_b[j] + pby * (d2y_b + dpy_b);  g_zeta[0][idx] = zy_b;
            zy_s = pay * zyo_s[j] + pby * (d2y_s + dpy_s);  g_zeta[2][idx] = zy_s;
        }
        if (pbx != 0.f) {
            zx_b = pax * zxo_b[j] + pbx * (d2x_b + dpx_b);  g_zeta[1][idx] = zx_b;
            zx_s = pax * zxo_s[j] + pbx * (d2x_s + dpx_s);  g_zeta[3][idx] = zx_s;
        }

        // ---- lap + leapfrog + Born + source ----
        float lap_b = d2y_b + d2x_b + dpy_b + dpx_b + zy_b + zx_b;
        float lap_s = d2y_s + d2x_s + dpy_s + dpx_s + zy_s + zx_s;
        float wn_b = v2 * lap_b + 2.f * wbv[j] - prevb[j];
        float wn_s = v2 * lap_s + 2.f * wsv[j] - prevs[j] + bsc * lap_b;
        if (y == g_spos[2 * s] && x == g_spos[2 * s + 1]) {
            wn_b += g_fbg[t * NS + s];
            wn_s += g_fsc[t * NS + s];
        }
        g_wb[nxt][idx] = wn_b;
        g_ws[nxt][idx] = wn_s;
    }
}

__global__ void finalize(const int* __restrict__ rloc, const int* __restrict__ rbloc,
                         void* __restrict__ out) {
    int i = blockIdx.x * blockDim.x + threadIdx.x;
    const float* wb0 = g_wb[0];   // NT even: newest field in buffer 0
    const float* ws0 = g_ws[0];
    if (i < SNP2) {
        out_st(out, i,        wb0[i]);
        out_st(out, SNP2 + i, ws0[i]);
    }
    if (i < 2 * NS * NREC) {      // record last step (t = NT-1)
        bool isbg = i < NS * NREC;
        int k = isbg ? i : i - NS * NREC;
        int s = k / NREC, r = k % NREC;
        const int* rl = isbg ? rbloc : rloc;
        int ry = clampi(rl[(s * NREC + r) * 2 + 0], 0, NYX - 1) + PAD;
        int rx = clampi(rl[(s * NREC + r) * 2 + 1], 0, NYX - 1) + PAD;
        const float* w = isbg ? wb0 : ws0;
        float val = w[s * NP2 + ry * NP + rx];
        int base = isbg ? (2 * SNP2) : (2 * SNP2 + NS * NREC * NT);
        out_st(out, base + (s * NREC + r) * NT + (NT - 1), val);
    }
}

extern "C" void kernel_launch(void* const* d_in, const int* in_sizes, int n_in,
                              void* d_out, int out_size, void* d_ws, size_t ws_size,
                              hipStream_t stream) {
    const void* v   = d_in[0];
    const void* sc  = d_in[1];
    const void* amp = d_in[2];
    const int* sloc  = (const int*)d_in[3];
    const int* rloc  = (const int*)d_in[4];
    const int* rbloc = (const int*)d_in[5];

    detect_mode<<<1, 64, 0, stream>>>(v);
    zero_state<<<(NP2 + 255) / 256, 256, 0, stream>>>();
    prep_pad<<<(NP2 + 255) / 256, 256, 0, stream>>>(v, sc);
    prep_src<<<(NT * NS + 255) / 256, 256, 0, stream>>>(amp, sloc, v, sc);

    dim3 grid(1, NP, 2);                 // row x shot-pair
    for (int t = 0; t < NT; ++t)
        step_fused<<<grid, 448, 0, stream>>>(t, rloc, rbloc, d_out);

    finalize<<<(SNP2 + 255) / 256, 256, 0, stream>>>(rloc, rbloc, d_out);
}

// Round 9
// 3847.290 us; speedup vs baseline: 1.7033x; 1.7033x over previous
//
#include <hip/hip_runtime.h>
#include <hip/hip_bf16.h>

// ScalarBorn: 4th-order FD scalar wave + Born scattering with CPML, MI355X.
// R9: R7 skeleton (row-block, two barriers, 300 dispatches) but 256 threads
// per block, 2 adjacent x-points per thread, float2 global traffic. Halves
// wave count and load/store instruction count vs R7. R8 (2 shots/block,
// heavy state) regressed -> blocks kept light.

constexpr int NYX  = 400;
constexpr int NS   = 4;
constexpr int NREC = 100;
constexpr int NT   = 300;
constexpr int PAD  = 22;
constexpr int NP   = 444;
constexpr int NP2  = NP * NP;          // 197136
constexpr int SNP2 = NS * NP2;         // 788544
constexpr float DT    = 0.0005f;
constexpr float INVH  = 0.2f;          // 1/DX
constexpr float INVH2 = 0.04f;         // 1/DX^2
constexpr float C1A = 1.0f / 12.0f;
constexpr float C1B = 2.0f / 3.0f;
constexpr float C2A = -1.0f / 12.0f;
constexpr float C2B = 4.0f / 3.0f;
constexpr float C2C = -2.5f;

__device__ __align__(16) float g_wb[2][SNP2];      // bg field ping-pong
__device__ __align__(16) float g_ws[2][SNP2];      // scattered field ping-pong
__device__ __align__(16) float g_psi[2][4][SNP2];  // [buf][py_b,px_b,py_s,px_s]
__device__ __align__(16) float g_zeta[4][SNP2];    // [zy_b,zx_b,zy_s,zx_s]
__device__ float g_v2dt2[NP2];
__device__ float g_bscale[NP2];
__device__ float g_pa[NP];
__device__ float g_pb[NP];
__device__ float g_fbg[NT * NS];
__device__ float g_fsc[NT * NS];
__device__ int   g_spos[2 * NS];
__device__ int   g_mode;               // 1 = bf16 io, 0 = f32 io

__device__ __forceinline__ int clampi(int v, int lo, int hi) {
    return v < lo ? lo : (v > hi ? hi : v);
}
__device__ __forceinline__ float in_ld(const void* p, int i) {
    if (g_mode) return __bfloat162float(((const __hip_bfloat16*)p)[i]);
    return ((const float*)p)[i];
}
__device__ __forceinline__ void out_st(void* p, int i, float v) {
    if (g_mode) ((__hip_bfloat16*)p)[i] = __float2bfloat16(v);
    else        ((float*)p)[i] = v;
}
// float2 row load at columns (2i, 2i+1) of row y; zero outside [0,NP)
__device__ __forceinline__ float2 ld2(const float* w, int y, int i) {
    if ((unsigned)y >= (unsigned)NP) return make_float2(0.f, 0.f);
    return *(const float2*)(w + y * NP + 2 * i);
}

__global__ void detect_mode(const void* vptr) {
    if (threadIdx.x == 0 && blockIdx.x == 0) {
        const __hip_bfloat16* p = (const __hip_bfloat16*)vptr;
        int ok = 1;
        for (int i = 0; i < 32; i += 2) {
            float f = __bfloat162float(p[i]);
            if (!(f >= 1000.f && f <= 3000.f)) ok = 0;
        }
        g_mode = ok;
    }
}

__global__ void zero_state() {
    int i = blockIdx.x * blockDim.x + threadIdx.x;
    if (i >= NP2) return;                 // SNP2/4 float4s per array == NP2
    float4 z = make_float4(0.f, 0.f, 0.f, 0.f);
    ((float4*)g_wb[0])[i] = z;  ((float4*)g_wb[1])[i] = z;
    ((float4*)g_ws[0])[i] = z;  ((float4*)g_ws[1])[i] = z;
    #pragma unroll
    for (int b = 0; b < 2; ++b)
        #pragma unroll
        for (int k = 0; k < 4; ++k) ((float4*)g_psi[b][k])[i] = z;
    #pragma unroll
    for (int k = 0; k < 4; ++k) ((float4*)g_zeta[k])[i] = z;
}

__global__ void prep_pad(const void* __restrict__ v, const void* __restrict__ sc) {
    int i = blockIdx.x * blockDim.x + threadIdx.x;
    if (i >= NP2) return;
    int y = i / NP, x = i % NP;
    int vy = clampi(y - PAD, 0, NYX - 1);
    int vx = clampi(x - PAD, 0, NYX - 1);
    float vv = in_ld(v, vy * NYX + vx);
    float vd = vv * DT;
    g_v2dt2[i] = vd * vd;
    float s = 0.f;
    if (y >= PAD && y < PAD + NYX && x >= PAD && x < PAD + NYX)
        s = in_ld(sc, (y - PAD) * NYX + (x - PAD));
    g_bscale[i] = 2.f * vv * s * DT * DT;
    if (i < NP) {
        float fi = (float)i;
        float f1 = fminf(fmaxf((22.f - fi) * 0.05f, 0.f), 1.f);
        float f2 = fminf(fmaxf((fi - 421.f) * 0.05f, 0.f), 1.f);
        float frac = fmaxf(f1, f2);
        float sigma = 259.0408229f * frac * frac;
        const float alpha = 78.53981634f;
        float a = expf(-(sigma + alpha) * DT);
        g_pa[i] = a;
        g_pb[i] = (sigma > 0.f) ? sigma / (sigma + alpha) * (a - 1.f) : 0.f;
    }
}

__global__ void prep_src(const void* __restrict__ amp, const int* __restrict__ sloc,
                         const void* __restrict__ v, const void* __restrict__ sc) {
    int i = blockIdx.x * blockDim.x + threadIdx.x;
    if (i >= NT * NS) return;
    int s = i % NS, t = i / NS;
    int ly = clampi(sloc[s * 2 + 0], 0, NYX - 1);
    int lx = clampi(sloc[s * 2 + 1], 0, NYX - 1);
    float a  = in_ld(amp, s * NT + t);
    float vv = in_ld(v,  ly * NYX + lx);
    float ss = in_ld(sc, ly * NYX + lx);
    g_fbg[i] = -a * vv * vv * DT * DT;
    g_fsc[i] = -2.f * a * vv * ss * DT * DT;
    if (i < NS) {
        g_spos[2 * i]     = ly + PAD;
        g_spos[2 * i + 1] = lx + PAD;
    }
}

// one fused timestep. Block = row y of shot s; 256 threads x 2 points.
__global__ void __launch_bounds__(256)
step_fused(int t, const int* __restrict__ rloc, const int* __restrict__ rbloc,
           void* __restrict__ out) {
    const int i = threadIdx.x;
    const int y = blockIdx.y;
    const int s = blockIdx.z;
    const int cur = t & 1, nxt = cur ^ 1;
    // logical col c at index c+2; pads [0,2) and [446,452)
    __shared__ float swb[452], sws[452], spxb[452], spxs[452];

    if (t > 0 && y == 0 && i < 2 * NREC) {    // record step t-1
        int r = i % NREC;
        bool isbg = i < NREC;
        const int* rl = isbg ? rbloc : rloc;
        int ry = clampi(rl[(s * NREC + r) * 2 + 0], 0, NYX - 1) + PAD;
        int rx = clampi(rl[(s * NREC + r) * 2 + 1], 0, NYX - 1) + PAD;
        const float* w = isbg ? g_wb[cur] : g_ws[cur];
        float val = w[s * NP2 + ry * NP + rx];
        int base = isbg ? (2 * SNP2) : (2 * SNP2 + NS * NREC * NT);
        out_st(out, base + (s * NREC + r) * NT + (t - 1), val);
    }

    const bool active = i < 222;
    const int x0 = 2 * i, x1 = x0 + 1;
    const int yx  = y * NP + x0;
    const int idx = s * NP2 + yx;
    const float* wb  = g_wb[cur] + s * NP2;
    const float* wsc = g_ws[cur] + s * NP2;

    float2 wvb = make_float2(0.f, 0.f), wvs = make_float2(0.f, 0.f);
    if (active) {
        wvb = *(const float2*)(wb + yx);
        wvs = *(const float2*)(wsc + yx);
        swb[x0 + 2] = wvb.x;  swb[x0 + 3] = wvb.y;
        sws[x0 + 2] = wvs.x;  sws[x0 + 3] = wvs.y;
    } else if (i == 222) {
        swb[0] = swb[1] = 0.f;   sws[0] = sws[1] = 0.f;
        spxb[0] = spxb[1] = 0.f; spxs[0] = spxs[1] = 0.f;
    } else if (i == 223) {
        #pragma unroll
        for (int k = 446; k < 452; ++k) {
            swb[k] = 0.f; sws[k] = 0.f; spxb[k] = 0.f; spxs[k] = 0.f;
        }
    }
    __syncthreads();

    // ---- x stencils from LDS + own psi_x updates ----
    const bool pxreg = (i <= 11 || i >= 210);  // x-PML / deriv-of-PML region
    float pbx0 = 0.f, pbx1 = 0.f, pax0 = 0.f, pax1 = 0.f;
    float d2x_b0 = 0.f, d2x_b1 = 0.f, d2x_s0 = 0.f, d2x_s1 = 0.f;
    float pxnb0 = 0.f, pxnb1 = 0.f, pxns0 = 0.f, pxns1 = 0.f;
    if (active) {
        const int b0 = x0 + 2;
        float bA = swb[b0 - 2], bB = swb[b0 - 1], bC = wvb.x,
              bD = wvb.y, bE = swb[b0 + 2], bF = swb[b0 + 3];
        float sA = sws[b0 - 2], sB = sws[b0 - 1], sC = wvs.x,
              sD = wvs.y, sE = sws[b0 + 2], sF = sws[b0 + 3];
        d2x_b0 = (C2A * (bA + bE) + C2B * (bB + bD) + C2C * bC) * INVH2;
        d2x_b1 = (C2A * (bB + bF) + C2B * (bC + bE) + C2C * bD) * INVH2;
        d2x_s0 = (C2A * (sA + sE) + C2B * (sB + sD) + C2C * sC) * INVH2;
        d2x_s1 = (C2A * (sB + sF) + C2B * (sC + sE) + C2C * sD) * INVH2;
        pbx0 = g_pb[x0]; pbx1 = g_pb[x1];
        pax0 = g_pa[x0]; pax1 = g_pa[x1];
        if (pxreg) {
            float2 pxo_b = *(const float2*)(g_psi[cur][1] + idx);
            float2 pxo_s = *(const float2*)(g_psi[cur][3] + idx);
            if (pbx0 != 0.f) {
                float dw_b = (C1A * bA - C1B * bB + C1B * bD - C1A * bE) * INVH;
                float dw_s = (C1A * sA - C1B * sB + C1B * sD - C1A * sE) * INVH;
                pxnb0 = pax0 * pxo_b.x + pbx0 * dw_b;
                pxns0 = pax0 * pxo_s.x + pbx0 * dw_s;
                g_psi[nxt][1][idx] = pxnb0;
                g_psi[nxt][3][idx] = pxns0;
            }
            if (pbx1 != 0.f) {
                float dw_b = (C1A * bB - C1B * bC + C1B * bE - C1A * bF) * INVH;
                float dw_s = (C1A * sB - C1B * sC + C1B * sE - C1A * sF) * INVH;
                pxnb1 = pax1 * pxo_b.y + pbx1 * dw_b;
                pxns1 = pax1 * pxo_s.y + pbx1 * dw_s;
                g_psi[nxt][1][idx + 1] = pxnb1;
                g_psi[nxt][3][idx + 1] = pxns1;
            }
        }
        spxb[b0] = pxnb0;  spxb[b0 + 1] = pxnb1;
        spxs[b0] = pxns0;  spxs[b0 + 1] = pxns1;
    }
    __syncthreads();
    if (!active) return;

    // ---- dpsi_x from LDS psi_x_new (4-tap, zero-padded) ----
    float dpx_b0 = 0.f, dpx_b1 = 0.f, dpx_s0 = 0.f, dpx_s1 = 0.f;
    if (pxreg) {
        const int b0 = x0 + 2;
        float pA = spxb[b0 - 2], pB = spxb[b0 - 1], pE = spxb[b0 + 2], pF = spxb[b0 + 3];
        float qA = spxs[b0 - 2], qB = spxs[b0 - 1], qE = spxs[b0 + 2], qF = spxs[b0 + 3];
        dpx_b0 = (C1A * pA - C1B * pB + C1B * pxnb1 - C1A * pE) * INVH;
        dpx_b1 = (C1A * pB - C1B * pxnb0 + C1B * pE - C1A * pF) * INVH;
        dpx_s0 = (C1A * qA - C1B * qB + C1B * pxns1 - C1A * qE) * INVH;
        dpx_s1 = (C1A * qB - C1B * pxns0 + C1B * qE - C1A * qF) * INVH;
    }

    // ---- y direction ----
    const float pby = g_pb[y];               // block-uniform
    const bool yframe = (y <= 23 || y >= 420);
    float d2y_b0, d2y_b1, d2y_s0, d2y_s1;
    float dpy_b0 = 0.f, dpy_b1 = 0.f, dpy_s0 = 0.f, dpy_s1 = 0.f;
    if (yframe) {
        float2 wyb[9], wys[9];               // rows y-4..y+4, cols x0,x1
        #pragma unroll
        for (int k = 0; k < 9; ++k) {
            if (k == 4) { wyb[4] = wvb; wys[4] = wvs; }
            else        { wyb[k] = ld2(wb, y - 4 + k, i); wys[k] = ld2(wsc, y - 4 + k, i); }
        }
        d2y_b0 = (C2A * (wyb[2].x + wyb[6].x) + C2B * (wyb[3].x + wyb[5].x) + C2C * wyb[4].x) * INVH2;
        d2y_b1 = (C2A * (wyb[2].y + wyb[6].y) + C2B * (wyb[3].y + wyb[5].y) + C2C * wyb[4].y) * INVH2;
        d2y_s0 = (C2A * (wys[2].x + wys[6].x) + C2B * (wys[3].x + wys[5].x) + C2C * wys[4].x) * INVH2;
        d2y_s1 = (C2A * (wys[2].y + wys[6].y) + C2B * (wys[3].y + wys[5].y) + C2C * wys[4].y) * INVH2;
        float2 pnb[5], pns[5];               // psi_y_new at rows y-2..y+2
        #pragma unroll
        for (int k = 0; k < 5; ++k) {
            int yy = y - 2 + k;
            float pbv = ((unsigned)yy < (unsigned)NP) ? g_pb[yy] : 0.f;  // uniform
            float2 b_ = make_float2(0.f, 0.f), s_ = make_float2(0.f, 0.f);
            if (pbv != 0.f) {
                float pav = g_pa[yy];
                float2 po0 = *(const float2*)(g_psi[cur][0] + s * NP2 + yy * NP + x0);
                float2 po2 = *(const float2*)(g_psi[cur][2] + s * NP2 + yy * NP + x0);
                float db0 = (C1A * wyb[k].x - C1B * wyb[k+1].x + C1B * wyb[k+3].x - C1A * wyb[k+4].x) * INVH;
                float db1 = (C1A * wyb[k].y - C1B * wyb[k+1].y + C1B * wyb[k+3].y - C1A * wyb[k+4].y) * INVH;
                float ds0 = (C1A * wys[k].x - C1B * wys[k+1].x + C1B * wys[k+3].x - C1A * wys[k+4].x) * INVH;
                float ds1 = (C1A * wys[k].y - C1B * wys[k+1].y + C1B * wys[k+3].y - C1A * wys[k+4].y) * INVH;
                b_.x = pav * po0.x + pbv * db0;  b_.y = pav * po0.y + pbv * db1;
                s_.x = pav * po2.x + pbv * ds0;  s_.y = pav * po2.y + pbv * ds1;
            }
            pnb[k] = b_;  pns[k] = s_;
        }
        dpy_b0 = (C1A * pnb[0].x - C1B * pnb[1].x + C1B * pnb[3].x - C1A * pnb[4].x) * INVH;
        dpy_b1 = (C1A * pnb[0].y - C1B * pnb[1].y + C1B * pnb[3].y - C1A * pnb[4].y) * INVH;
        dpy_s0 = (C1A * pns[0].x - C1B * pns[1].x + C1B * pns[3].x - C1A * pns[4].x) * INVH;
        dpy_s1 = (C1A * pns[0].y - C1B * pns[1].y + C1B * pns[3].y - C1A * pns[4].y) * INVH;
        if (pby != 0.f) {
            *(float2*)(g_psi[nxt][0] + idx) = pnb[2];
            *(float2*)(g_psi[nxt][2] + idx) = pns[2];
        }
    } else {                                 // interior rows: light path
        float2 bm2 = *(const float2*)(wb + yx - 2 * NP);
        float2 bm1 = *(const float2*)(wb + yx - NP);
        float2 bp1 = *(const float2*)(wb + yx + NP);
        float2 bp2 = *(const float2*)(wb + yx + 2 * NP);
        float2 sm2 = *(const float2*)(wsc + yx - 2 * NP);
        float2 sm1 = *(const float2*)(wsc + yx - NP);
        float2 sp1 = *(const float2*)(wsc + yx + NP);
        float2 sp2 = *(const float2*)(wsc + yx + 2 * NP);
        d2y_b0 = (C2A * (bm2.x + bp2.x) + C2B * (bm1.x + bp1.x) + C2C * wvb.x) * INVH2;
        d2y_b1 = (C2A * (bm2.y + bp2.y) + C2B * (bm1.y + bp1.y) + C2C * wvb.y) * INVH2;
        d2y_s0 = (C2A * (sm2.x + sp2.x) + C2B * (sm1.x + sp1.x) + C2C * wvs.x) * INVH2;
        d2y_s1 = (C2A * (sm2.y + sp2.y) + C2B * (sm1.y + sp1.y) + C2C * wvs.y) * INVH2;
    }

    // ---- zeta (in-place, own points) ----
    float zy_b0 = 0.f, zy_b1 = 0.f, zy_s0 = 0.f, zy_s1 = 0.f;
    float zx_b0 = 0.f, zx_b1 = 0.f, zx_s0 = 0.f, zx_s1 = 0.f;
    if (pby != 0.f) {
        float pay = g_pa[y];
        float2 zo0 = *(const float2*)(g_zeta[0] + idx);
        float2 zo2 = *(const float2*)(g_zeta[2] + idx);
        zy_b0 = pay * zo0.x + pby * (d2y_b0 + dpy_b0);
        zy_b1 = pay * zo0.y + pby * (d2y_b1 + dpy_b1);
        zy_s0 = pay * zo2.x + pby * (d2y_s0 + dpy_s0);
        zy_s1 = pay * zo2.y + pby * (d2y_s1 + dpy_s1);
        *(float2*)(g_zeta[0] + idx) = make_float2(zy_b0, zy_b1);
        *(float2*)(g_zeta[2] + idx) = make_float2(zy_s0, zy_s1);
    }
    if (pxreg) {
        float2 zo1 = *(const float2*)(g_zeta[1] + idx);
        float2 zo3 = *(const float2*)(g_zeta[3] + idx);
        if (pbx0 != 0.f) {
            zx_b0 = pax0 * zo1.x + pbx0 * (d2x_b0 + dpx_b0);
            zx_s0 = pax0 * zo3.x + pbx0 * (d2x_s0 + dpx_s0);
            g_zeta[1][idx] = zx_b0;  g_zeta[3][idx] = zx_s0;
        }
        if (pbx1 != 0.f) {
            zx_b1 = pax1 * zo1.y + pbx1 * (d2x_b1 + dpx_b1);
            zx_s1 = pax1 * zo3.y + pbx1 * (d2x_s1 + dpx_s1);
            g_zeta[1][idx + 1] = zx_b1;  g_zeta[3][idx + 1] = zx_s1;
        }
    }

    // ---- lap + leapfrog + Born + source ----
    float2 v2   = *(const float2*)(g_v2dt2 + yx);
    float2 bsc  = *(const float2*)(g_bscale + yx);
    float2 prvb = *(const float2*)(g_wb[nxt] + idx);
    float2 prvs = *(const float2*)(g_ws[nxt] + idx);
    float lap_b0 = d2y_b0 + d2x_b0 + dpy_b0 + dpx_b0 + zy_b0 + zx_b0;
    float lap_b1 = d2y_b1 + d2x_b1 + dpy_b1 + dpx_b1 + zy_b1 + zx_b1;
    float lap_s0 = d2y_s0 + d2x_s0 + dpy_s0 + dpx_s0 + zy_s0 + zx_s0;
    float lap_s1 = d2y_s1 + d2x_s1 + dpy_s1 + dpx_s1 + zy_s1 + zx_s1;
    float wn_b0 = v2.x * lap_b0 + 2.f * wvb.x - prvb.x;
    float wn_b1 = v2.y * lap_b1 + 2.f * wvb.y - prvb.y;
    float wn_s0 = v2.x * lap_s0 + 2.f * wvs.x - prvs.x + bsc.x * lap_b0;
    float wn_s1 = v2.y * lap_s1 + 2.f * wvs.y - prvs.y + bsc.y * lap_b1;
    if (y == g_spos[2 * s]) {
        int sx = g_spos[2 * s + 1];
        if (sx == x0)      { wn_b0 += g_fbg[t * NS + s]; wn_s0 += g_fsc[t * NS + s]; }
        else if (sx == x1) { wn_b1 += g_fbg[t * NS + s]; wn_s1 += g_fsc[t * NS + s]; }
    }
    *(float2*)(g_wb[nxt] + idx) = make_float2(wn_b0, wn_b1);
    *(float2*)(g_ws[nxt] + idx) = make_float2(wn_s0, wn_s1);
}

__global__ void finalize(const int* __restrict__ rloc, const int* __restrict__ rbloc,
                         void* __restrict__ out) {
    int i = blockIdx.x * blockDim.x + threadIdx.x;
    const float* wb0 = g_wb[0];   // NT even: newest field in buffer 0
    const float* ws0 = g_ws[0];
    if (i < SNP2) {
        out_st(out, i,        wb0[i]);
        out_st(out, SNP2 + i, ws0[i]);
    }
    if (i < 2 * NS * NREC) {      // record last step (t = NT-1)
        bool isbg = i < NS * NREC;
        int k = isbg ? i : i - NS * NREC;
        int s = k / NREC, r = k % NREC;
        const int* rl = isbg ? rbloc : rloc;
        int ry = clampi(rl[(s * NREC + r) * 2 + 0], 0, NYX - 1) + PAD;
        int rx = clampi(rl[(s * NREC + r) * 2 + 1], 0, NYX - 1) + PAD;
        const float* w = isbg ? wb0 : ws0;
        float val = w[s * NP2 + ry * NP + rx];
        int base = isbg ? (2 * SNP2) : (2 * SNP2 + NS * NREC * NT);
        out_st(out, base + (s * NREC + r) * NT + (NT - 1), val);
    }
}

extern "C" void kernel_launch(void* const* d_in, const int* in_sizes, int n_in,
                              void* d_out, int out_size, void* d_ws, size_t ws_size,
                              hipStream_t stream) {
    const void* v   = d_in[0];
    const void* sc  = d_in[1];
    const void* amp = d_in[2];
    const int* sloc  = (const int*)d_in[3];
    const int* rloc  = (const int*)d_in[4];
    const int* rbloc = (const int*)d_in[5];

    detect_mode<<<1, 64, 0, stream>>>(v);
    zero_state<<<(NP2 + 255) / 256, 256, 0, stream>>>();
    prep_pad<<<(NP2 + 255) / 256, 256, 0, stream>>>(v, sc);
    prep_src<<<(NT * NS + 255) / 256, 256, 0, stream>>>(amp, sloc, v, sc);

    dim3 grid(1, NP, NS);
    for (int t = 0; t < NT; ++t)
        step_fused<<<grid, 256, 0, stream>>>(t, rloc, rbloc, d_out);

    finalize<<<(SNP2 + 255) / 256, 256, 0, stream>>>(rloc, rbloc, d_out);
}